// Round 6
// baseline (654.893 us; speedup 1.0000x reference)
//
#include <hip/hip_runtime.h>
#include <hip/hip_bf16.h>
#include <stdint.h>

// B=32768, S=1, I=128, H=256, L=2, A=32
#define NB 32768
#define ID 128
#define HD 256
#define AD 32
#define BM 32          // batch rows per block (40KB LDS -> 4 blocks/CU)
#define MT (BM / 16)   // 16-row MFMA tiles per block
#define NTH 256        // 4 waves
#define NBLK (NB / BM) // 1024 blocks

typedef unsigned int u32;
typedef unsigned short u16;
typedef __attribute__((ext_vector_type(8))) short bf16x8;  // 8 bf16 = 4 VGPR
typedef __attribute__((ext_vector_type(4))) float f32x4;
typedef __attribute__((ext_vector_type(2))) u32 u32x2;

// bf16 weight workspace layout (elements)
#define OFF_W0X 0               // 768x128
#define OFF_W0H 98304           // 768x256
#define OFF_W1X 294912          // 768x256
#define OFF_W1H 491520          // 768x256
#define OFF_WHD 688128          // 48x256 (wp rows 0-31, wv row 32, 0 pad)
#define W_TOTAL 700416

__device__ __forceinline__ u16 f2bf(float f) {  // round-to-nearest-even
    u32 u = __builtin_bit_cast(u32, f);
    return (u16)((u + 0x7FFFu + ((u >> 16) & 1u)) >> 16);
}
__device__ __forceinline__ float bf2f(u16 b) {
    return __builtin_bit_cast(float, (u32)b << 16);
}
__device__ __forceinline__ float sigf(float v) { return 1.0f / (1.0f + __expf(-v)); }
__device__ __forceinline__ float tanh_fast(float v) { return 1.0f - 2.0f / (1.0f + __expf(2.0f * v)); }

__global__ void prep_weights(const float* __restrict__ wih0, const float* __restrict__ whh0,
                             const float* __restrict__ wih1, const float* __restrict__ whh1,
                             const float* __restrict__ wp, const float* __restrict__ wv,
                             u16* __restrict__ wb) {
    int i = blockIdx.x * blockDim.x + threadIdx.x;
    if (i >= W_TOTAL) return;
    float v;
    if (i < OFF_W0H)      v = wih0[i];
    else if (i < OFF_W1X) v = whh0[i - OFF_W0H];
    else if (i < OFF_W1H) v = wih1[i - OFF_W1X];
    else if (i < OFF_WHD) v = whh1[i - OFF_W1H];
    else {
        int j = i - OFF_WHD;
        int r = j >> 8, k = j & 255;
        v = (r < AD) ? wp[j] : ((r == AD) ? wv[k] : 0.0f);
    }
    wb[i] = f2bf(v);
}

// swizzled LDS byte address: row-major tile, rowstride bytes, XOR (row&7)<<4
#define SWZ(row, kbyte, rowstride) ((((row) * (rowstride)) + (kbyte)) ^ (((row) & 7) << 4))

#define MFMA(a, b, c) __builtin_amdgcn_mfma_f32_16x16x32_bf16((a), (b), (c), 0, 0, 0)

// Pipelined gate GEMM for one 16-col chunk: unified step stream (x-side steps
// then h-side steps), depth-2 register double-buffer on the weight loads.
template<int KA>
__device__ __forceinline__ void gate_gemm_pipe(
    const char* __restrict__ Ax, const char* __restrict__ Ah,
    const u16* __restrict__ Wx, const u16* __restrict__ Wh,
    int col, int lane,
    f32x4 accr[MT], f32x4 accz[MT], f32x4 accni[MT], f32x4 accnh[MT])
{
    constexpr int NX = KA / 32;     // x-side steps
    constexpr int NS = NX + 8;      // + h-side steps (K=256)
    const int krow = (lane >> 4) * 8;
    const int arow = lane & 15;

    const u16* bx0 = Wx + (size_t)col * KA + krow;
    const u16* bx1 = Wx + (size_t)(HD + col) * KA + krow;
    const u16* bx2 = Wx + (size_t)(2 * HD + col) * KA + krow;
    const u16* bh0 = Wh + (size_t)col * HD + krow;
    const u16* bh1 = Wh + (size_t)(HD + col) * HD + krow;
    const u16* bh2 = Wh + (size_t)(2 * HD + col) * HD + krow;

#define WLD(s, g) ( (s) < NX \
    ? *(const bf16x8*)(((g) == 0 ? bx0 : (g) == 1 ? bx1 : bx2) + (s) * 32) \
    : *(const bf16x8*)(((g) == 0 ? bh0 : (g) == 1 ? bh1 : bh2) + ((s) - NX) * 32) )

    bf16x8 wA0 = WLD(0, 0), wA1 = WLD(0, 1), wA2 = WLD(0, 2);
    bf16x8 wB0 = WLD(1, 0), wB1 = WLD(1, 1), wB2 = WLD(1, 2);

#pragma unroll
    for (int s = 0; s < NS; ++s) {
        bf16x8 w0 = (s & 1) ? wB0 : wA0;
        bf16x8 w1 = (s & 1) ? wB1 : wA1;
        bf16x8 w2 = (s & 1) ? wB2 : wA2;
        if (s + 2 < NS) {
            if (s & 1) { wB0 = WLD(s + 2, 0); wB1 = WLD(s + 2, 1); wB2 = WLD(s + 2, 2); }
            else       { wA0 = WLD(s + 2, 0); wA1 = WLD(s + 2, 1); wA2 = WLD(s + 2, 2); }
        }
        const bool xside = (s < NX);
        const int kb = (xside ? s * 32 : (s - NX) * 32) + krow;
#pragma unroll
        for (int m = 0; m < MT; ++m) {
            const int row = m * 16 + arow;
            bf16x8 a = xside ? *(const bf16x8*)(Ax + SWZ(row, kb * 2, KA * 2))
                             : *(const bf16x8*)(Ah + SWZ(row, kb * 2, 512));
            accr[m] = MFMA(a, w0, accr[m]);
            accz[m] = MFMA(a, w1, accz[m]);
            if (xside) accni[m] = MFMA(a, w2, accni[m]);
            else       accnh[m] = MFMA(a, w2, accnh[m]);
        }
    }
#undef WLD
}

// Full layer: 4 col-chunks of 64 (wave takes 16 cols each). h_prev read from LDS
// bf16 (Ah), h' kept bf16 in registers (st) for the post-sync LDS stash.
template<int KA>
__device__ __forceinline__ void gru_layer_mfma(
    const char* __restrict__ Ax, const char* __restrict__ Ah,
    const u16* __restrict__ Wx, const u16* __restrict__ Wh,
    const float* __restrict__ bi, const float* __restrict__ bh,
    int lane, int w, u32 st[4][MT][2])
{
#pragma unroll
    for (int c = 0; c < 4; ++c) {
        const int col = c * 64 + (w << 4) + (lane & 15);
        const float br  = bi[col] + bh[col];
        const float bz  = bi[HD + col] + bh[HD + col];
        const float bni = bi[2 * HD + col];
        const float bnh = bh[2 * HD + col];
        f32x4 accr[MT], accz[MT], accni[MT], accnh[MT];
#pragma unroll
        for (int m = 0; m < MT; ++m) {
            accr[m]  = f32x4{br, br, br, br};
            accz[m]  = f32x4{bz, bz, bz, bz};
            accni[m] = f32x4{bni, bni, bni, bni};
            accnh[m] = f32x4{bnh, bnh, bnh, bnh};
        }
        gate_gemm_pipe<KA>(Ax, Ah, Wx, Wh, col, lane, accr, accz, accni, accnh);
#pragma unroll
        for (int m = 0; m < MT; ++m) {
            const int rowg = m * 16 + ((lane >> 4) << 2);   // C layout: row=(l>>4)*4+reg
#pragma unroll
            for (int pq = 0; pq < 2; ++pq) {
                u32 pk = 0;
#pragma unroll
                for (int q2 = 0; q2 < 2; ++q2) {
                    const int q = pq * 2 + q2;
                    float rg = sigf(accr[m][q]);
                    float zg = sigf(accz[m][q]);
                    float n  = tanh_fast(accni[m][q] + rg * accnh[m][q]);
                    float hp = bf2f(*(const u16*)(Ah + SWZ(rowg + q, col * 2, 512)));
                    float hv = (1.0f - zg) * n + zg * hp;
                    pk |= (u32)f2bf(hv) << (16 * q2);
                }
                st[c][m][pq] = pk;
            }
        }
    }
}

__device__ __forceinline__ void write_stash(char* __restrict__ R, u32 st[4][MT][2],
                                            int lane, int w) {
#pragma unroll
    for (int c = 0; c < 4; ++c)
#pragma unroll
        for (int m = 0; m < MT; ++m) {
            const int colb = (c * 64 + (w << 4) + (lane & 15)) * 2;
            const int rowg = m * 16 + ((lane >> 4) << 2);
            *(u16*)(R + SWZ(rowg + 0, colb, 512)) = (u16)(st[c][m][0]);
            *(u16*)(R + SWZ(rowg + 1, colb, 512)) = (u16)(st[c][m][0] >> 16);
            *(u16*)(R + SWZ(rowg + 2, colb, 512)) = (u16)(st[c][m][1]);
            *(u16*)(R + SWZ(rowg + 3, colb, 512)) = (u16)(st[c][m][1] >> 16);
        }
}

// Coalesced fp32 dump of a 32x256 bf16 LDS tile: full-line nontemporal streams.
__device__ __forceinline__ void dump_h(const char* __restrict__ R,
                                       float* __restrict__ g, int row0, int t) {
#pragma unroll
    for (int it = 0; it < 8; ++it) {
        int i = t + it * NTH;         // 2048 float4 = 32 rows x 64 float4
        int row = i >> 6, f4 = i & 63;
        u32x2 b = *(const u32x2*)(R + SWZ(row, f4 * 8, 512));
        f32x4 v;
        v[0] = __builtin_bit_cast(float, (b[0] & 0xFFFFu) << 16);
        v[1] = __builtin_bit_cast(float, b[0] & 0xFFFF0000u);
        v[2] = __builtin_bit_cast(float, (b[1] & 0xFFFFu) << 16);
        v[3] = __builtin_bit_cast(float, b[1] & 0xFFFF0000u);
        __builtin_nontemporal_store(v, (f32x4*)(g + (size_t)(row0 + row) * HD + f4 * 4));
    }
}

__global__ __launch_bounds__(NTH, 4) void gru_mfma(
    const float* __restrict__ x, const float* __restrict__ h,
    const float* __restrict__ bih0, const float* __restrict__ bhh0,
    const float* __restrict__ bih1, const float* __restrict__ bhh1,
    const float* __restrict__ bp, const float* __restrict__ bv,
    const u16* __restrict__ wb, float* __restrict__ out)
{
    __shared__ uint4 lds4[40960 / 16];           // 40 KB -> 4 blocks/CU
    char* lds = (char*)lds4;
    char* R1 = lds;             // x tile: 32 x 128 bf16, stride 256B (swz) = 8KB
    char* R2 = lds + 8192;      // h0 -> h0' -> h1' : 32 x 256 bf16, stride 512B = 16KB
    char* R3 = lds + 24576;     // h1 : 16KB

    const int t = threadIdx.x;
    const int lane = t & 63;
    const int w = t >> 6;
    const int row0 = blockIdx.x * BM;

    const u16* W0x = wb + OFF_W0X;
    const u16* W0h = wb + OFF_W0H;
    const u16* W1x = wb + OFF_W1X;
    const u16* W1h = wb + OFF_W1H;
    const u16* Whd = wb + OFF_WHD;

    float* out_logits = out;
    float* out_value  = out + (size_t)NB * AD;
    float* out_h0     = out_value + NB;
    float* out_h1     = out_h0 + (size_t)NB * HD;

    // ---- stage x, h0, h1 (fp32 -> bf16, swizzled, nontemporal f32x4 reads) ----
    {
        const f32x4* xg = (const f32x4*)(x + (size_t)row0 * ID);
#pragma unroll
        for (int it = 0; it < 4; ++it) {
            int i = t + it * NTH;                 // 1024 float4
            f32x4 v = __builtin_nontemporal_load(xg + i);
            int rowi = i >> 5;                    // 32 float4/row
            int kb = (i & 31) * 8;                // bf16 byte offset
            u32x2 b;
            b[0] = (u32)f2bf(v[0]) | ((u32)f2bf(v[1]) << 16);
            b[1] = (u32)f2bf(v[2]) | ((u32)f2bf(v[3]) << 16);
            *(u32x2*)(R1 + SWZ(rowi, kb, 256)) = b;
        }
        const f32x4* h0g = (const f32x4*)(h + (size_t)row0 * HD);
        const f32x4* h1g = (const f32x4*)(h + (size_t)NB * HD + (size_t)row0 * HD);
#pragma unroll
        for (int it = 0; it < 8; ++it) {
            int i = t + it * NTH;                 // 2048 float4
            int rowi = i >> 6;                    // 64 float4/row
            int kb = (i & 63) * 8;
            f32x4 v0 = __builtin_nontemporal_load(h0g + i);
            u32x2 b0;
            b0[0] = (u32)f2bf(v0[0]) | ((u32)f2bf(v0[1]) << 16);
            b0[1] = (u32)f2bf(v0[2]) | ((u32)f2bf(v0[3]) << 16);
            *(u32x2*)(R2 + SWZ(rowi, kb, 512)) = b0;
            f32x4 v1 = __builtin_nontemporal_load(h1g + i);
            u32x2 b1;
            b1[0] = (u32)f2bf(v1[0]) | ((u32)f2bf(v1[1]) << 16);
            b1[1] = (u32)f2bf(v1[2]) | ((u32)f2bf(v1[3]) << 16);
            *(u32x2*)(R3 + SWZ(rowi, kb, 512)) = b1;
        }
    }
    __syncthreads();

    u32 st[4][MT][2];
    // ---- layer 0: A_x = x (R1), A_h = h_prev = h0 (R2) ----
    gru_layer_mfma<ID>(R1, R2, W0x, W0h, bih0, bhh0, lane, w, st);
    __syncthreads();                 // all waves done reading h0
    write_stash(R2, st, lane, w);    // R2 := h0' (bf16)
    __syncthreads();
    dump_h(R2, out_h0, row0, t);     // coalesced fp32 h0' writes

    // ---- layer 1: A_x = h0' (R2), A_h = h_prev = h1 (R3) ----
    gru_layer_mfma<HD>(R2, R3, W1x, W1h, bih1, bhh1, lane, w, st);
    __syncthreads();                 // all waves done reading h0'/h1
    write_stash(R2, st, lane, w);    // R2 := h1' (bf16)
    __syncthreads();
    dump_h(R2, out_h1, row0, t);     // coalesced fp32 h1' writes

    // ---- heads: [logits(32) | value(1) | pad] = h1' @ Whd^T, N=48, K=256 ----
    if (w < MT) {
        const int m = w;                          // wave w -> rows m*16..+15
        const int arow = lane & 15;
        const int krow = (lane >> 4) * 8;
        float b0 = bp[arow], b1 = bp[16 + arow], b2 = bv[0];
        f32x4 acc[3];
        acc[0] = f32x4{b0, b0, b0, b0};
        acc[1] = f32x4{b1, b1, b1, b1};
        acc[2] = f32x4{b2, b2, b2, b2};
#pragma unroll
        for (int ks = 0; ks < 8; ++ks) {
            const int kb = ks * 32 + krow;
            const int row = m * 16 + arow;
            bf16x8 a = *(const bf16x8*)(R2 + SWZ(row, kb * 2, 512));
#pragma unroll
            for (int f = 0; f < 3; ++f) {
                bf16x8 wf = *(const bf16x8*)(Whd + (size_t)(f * 16 + arow) * HD + kb);
                acc[f] = MFMA(a, wf, acc[f]);
            }
        }
        const int rowg = m * 16 + ((lane >> 4) << 2);
#pragma unroll
        for (int q = 0; q < 4; ++q) {
            __builtin_nontemporal_store(acc[0][q],
                &out_logits[(size_t)(row0 + rowg + q) * AD + arow]);
            __builtin_nontemporal_store(acc[1][q],
                &out_logits[(size_t)(row0 + rowg + q) * AD + 16 + arow]);
        }
        if (arow == 0) {
#pragma unroll
            for (int q = 0; q < 4; ++q)
                __builtin_nontemporal_store(acc[2][q], &out_value[row0 + rowg + q]);
        }
    }
}

extern "C" void kernel_launch(void* const* d_in, const int* in_sizes, int n_in,
                              void* d_out, int out_size, void* d_ws, size_t ws_size,
                              hipStream_t stream) {
    const float* x    = (const float*)d_in[0];
    const float* h    = (const float*)d_in[1];
    const float* wih0 = (const float*)d_in[2];
    const float* whh0 = (const float*)d_in[3];
    const float* bih0 = (const float*)d_in[4];
    const float* bhh0 = (const float*)d_in[5];
    const float* wih1 = (const float*)d_in[6];
    const float* whh1 = (const float*)d_in[7];
    const float* bih1 = (const float*)d_in[8];
    const float* bhh1 = (const float*)d_in[9];
    const float* wp   = (const float*)d_in[10];
    const float* bp   = (const float*)d_in[11];
    const float* wv   = (const float*)d_in[12];
    const float* bv   = (const float*)d_in[13];

    u16* wb = (u16*)d_ws;   // 1.37 MB bf16 weights
    prep_weights<<<(W_TOTAL + 255) / 256, 256, 0, stream>>>(wih0, whh0, wih1, whh1, wp, wv, wb);
    gru_mfma<<<NBLK, NTH, 0, stream>>>(x, h, bih0, bhh0, bih1, bhh1, bp, bv, wb, (float*)d_out);
}

// Round 7
// 253.612 us; speedup vs baseline: 2.5823x; 2.5823x over previous
//
#include <hip/hip_runtime.h>
#include <hip/hip_bf16.h>
#include <stdint.h>

// B=32768, S=1, I=128, H=256, L=2, A=32
#define NB 32768
#define ID 128
#define HD 256
#define AD 32
#define BM 32          // batch rows per block
#define MT 2           // 16-row MFMA tiles per block
#define NTH 256        // 4 waves
#define NBLK (NB / BM) // 1024 blocks

typedef unsigned int u32;
typedef unsigned short u16;
typedef __attribute__((ext_vector_type(8))) short bf16x8;  // 8 bf16 = 4 VGPR
typedef __attribute__((ext_vector_type(4))) float f32x4;
typedef __attribute__((ext_vector_type(2))) u32 u32x2;

// bf16 weight workspace layout (elements)
#define OFF_W0X 0               // 768x128
#define OFF_W0H 98304           // 768x256
#define OFF_W1X 294912          // 768x256
#define OFF_W1H 491520          // 768x256
#define OFF_WHD 688128          // 48x256 (wp rows 0-31, wv row 32, 0 pad)
#define W_TOTAL 700416

__device__ __forceinline__ u16 f2bf(float f) {  // round-to-nearest-even
    u32 u = __builtin_bit_cast(u32, f);
    return (u16)((u + 0x7FFFu + ((u >> 16) & 1u)) >> 16);
}
__device__ __forceinline__ float bf2f(u16 b) {
    return __builtin_bit_cast(float, (u32)b << 16);
}
__device__ __forceinline__ float sigf(float v) { return 1.0f / (1.0f + __expf(-v)); }
__device__ __forceinline__ float tanh_fast(float v) { return 1.0f - 2.0f / (1.0f + __expf(2.0f * v)); }

__global__ void prep_weights(const float* __restrict__ wih0, const float* __restrict__ whh0,
                             const float* __restrict__ wih1, const float* __restrict__ whh1,
                             const float* __restrict__ wp, const float* __restrict__ wv,
                             u16* __restrict__ wb) {
    int i = blockIdx.x * blockDim.x + threadIdx.x;
    if (i >= W_TOTAL) return;
    float v;
    if (i < OFF_W0H)      v = wih0[i];
    else if (i < OFF_W1X) v = whh0[i - OFF_W0H];
    else if (i < OFF_W1H) v = wih1[i - OFF_W1X];
    else if (i < OFF_WHD) v = whh1[i - OFF_W1H];
    else {
        int j = i - OFF_WHD;
        int r = j >> 8, k = j & 255;
        v = (r < AD) ? wp[j] : ((r == AD) ? wv[k] : 0.0f);
    }
    wb[i] = f2bf(v);
}

// swizzled LDS byte address for ACTIVATION tiles: XOR (row&7)<<4
#define SWZ(row, kbyte, rowstride) ((((row) * (rowstride)) + (kbyte)) ^ (((row) & 7) << 4))

#define MFMA(a, b, c) __builtin_amdgcn_mfma_f32_16x16x32_bf16((a), (b), (c), 0, 0, 0)

// ---- weight slab: 12 KB = [3 gates][64 cols][32 K] bf16. LDS = 192 rows x 64B.
// 16B-slot within each row XOR-swizzled by ((row>>1)&3); since global_load_lds
// writes linearly (uniform base + lane*16B), the swizzle is applied by
// PRE-SWIZZLING the per-lane GLOBAL source (rule: both-sides-or-neither).
template<int KXS>   // x-side k-steps (KA/32): 4 (layer0) or 8 (layer1)
__device__ __forceinline__ void stage_step(char* dst, const u16* __restrict__ Wx,
                                           const u16* __restrict__ Wh,
                                           int s, int cbase, int w, int lane) {
    const bool xside = s < KXS;
    const u16* W = xside ? Wx : Wh;
    const int KW = xside ? KXS * 32 : HD;
    const int ks = xside ? s : s - KXS;
#pragma unroll
    for (int i = 0; i < 3; ++i) {
        const int unit = w * 3 + i;                 // 1KB unit 0..11 (uniform per wave)
        const int ldsrow = unit * 16 + (lane >> 2); // 64B row 0..191
        const int slot = lane & 3;                  // 16B slot within row
        const int g = ldsrow >> 6, colr = ldsrow & 63;
        const int kslot = slot ^ ((ldsrow >> 1) & 3);
        const u16* src = W + (size_t)(g * HD + cbase + colr) * KW + ks * 32 + kslot * 8;
        __builtin_amdgcn_global_load_lds(
            (const __attribute__((address_space(1))) void*)src,
            (__attribute__((address_space(3))) void*)(dst + unit * 1024),
            16, 0, 0);
    }
}

__device__ __forceinline__ bf16x8 read_wfrag(const char* buf, int g, int colw, int kg) {
    const int row = g * 64 + colw;
    const int slot = kg ^ ((row >> 1) & 3);
    return *(const bf16x8*)(buf + row * 64 + slot * 16);
}

// One GRU layer: 4 col-slabs of 64; per slab, 2-phase K-loop with LDS-staged
// weights (STAGE(next) || compute(cur), barrier per step). h_prev from LDS bf16.
template<int KXS>
__device__ __forceinline__ void gru_layer_v3(
    const char* __restrict__ Ax, const char* __restrict__ Ah,
    char* __restrict__ wb0, char* __restrict__ wb1,
    const u16* __restrict__ Wx, const u16* __restrict__ Wh,
    const float* __restrict__ bi, const float* __restrict__ bh,
    int lane, int w, u32 st[4][MT][2])
{
    constexpr int NS = KXS + 8;          // total steps (even: 12 or 16)
    const int arow = lane & 15;
    const int kg = lane >> 4;
    const int colw = (w << 4) + arow;    // this lane's col within the 64-col slab

#pragma unroll 1
    for (int c = 0; c < 4; ++c) {
        const int cbase = c * 64;
        const int col = cbase + colw;
        const float br  = bi[col] + bh[col];
        const float bz  = bi[HD + col] + bh[HD + col];
        const float bni = bi[2 * HD + col];
        const float bnh = bh[2 * HD + col];
        f32x4 accr[MT], accz[MT], accni[MT], accnh[MT];
#pragma unroll
        for (int m = 0; m < MT; ++m) {
            accr[m]  = f32x4{br, br, br, br};
            accz[m]  = f32x4{bz, bz, bz, bz};
            accni[m] = f32x4{bni, bni, bni, bni};
            accnh[m] = f32x4{bnh, bnh, bnh, bnh};
        }

        stage_step<KXS>(wb0, Wx, Wh, 0, cbase, w, lane);   // prologue
        __syncthreads();                                    // (drains vmcnt)

#pragma unroll
        for (int s = 0; s < NS; ++s) {
            char* cur = (s & 1) ? wb1 : wb0;
            char* nxt = (s & 1) ? wb0 : wb1;
            if (s + 1 < NS)
                stage_step<KXS>(nxt, Wx, Wh, s + 1, cbase, w, lane);
            bf16x8 w0 = read_wfrag(cur, 0, colw, kg);
            bf16x8 w1 = read_wfrag(cur, 1, colw, kg);
            bf16x8 w2 = read_wfrag(cur, 2, colw, kg);
            const bool xside = (s < KXS);
            const int kb2 = ((xside ? s : s - KXS) * 32 + kg * 8) * 2;  // byte k-offset
#pragma unroll
            for (int m = 0; m < MT; ++m) {
                const int row = m * 16 + arow;
                bf16x8 a = xside ? *(const bf16x8*)(Ax + SWZ(row, kb2, KXS * 64))
                                 : *(const bf16x8*)(Ah + SWZ(row, kb2, 512));
                accr[m] = MFMA(a, w0, accr[m]);
                accz[m] = MFMA(a, w1, accz[m]);
                if (xside) accni[m] = MFMA(a, w2, accni[m]);
                else       accnh[m] = MFMA(a, w2, accnh[m]);
            }
            __syncthreads();   // staged data visible + protects buffer reuse
        }

        // epilogue: gates -> h' (bf16 stash); h_prev read from LDS A_h tile
#pragma unroll
        for (int m = 0; m < MT; ++m) {
            const int rowg = m * 16 + ((lane >> 4) << 2);   // C layout: row=(l>>4)*4+reg
#pragma unroll
            for (int pq = 0; pq < 2; ++pq) {
                u32 pk = 0;
#pragma unroll
                for (int q2 = 0; q2 < 2; ++q2) {
                    const int q = pq * 2 + q2;
                    float rg = sigf(accr[m][q]);
                    float zg = sigf(accz[m][q]);
                    float n  = tanh_fast(accni[m][q] + rg * accnh[m][q]);
                    float hp = bf2f(*(const u16*)(Ah + SWZ(rowg + q, col * 2, 512)));
                    float hv = (1.0f - zg) * n + zg * hp;
                    pk |= (u32)f2bf(hv) << (16 * q2);
                }
                st[c][m][pq] = pk;
            }
        }
    }
}

__device__ __forceinline__ void write_stash(char* __restrict__ R, u32 st[4][MT][2],
                                            int lane, int w) {
#pragma unroll
    for (int c = 0; c < 4; ++c)
#pragma unroll
        for (int m = 0; m < MT; ++m) {
            const int colb = (c * 64 + (w << 4) + (lane & 15)) * 2;
            const int rowg = m * 16 + ((lane >> 4) << 2);
            *(u16*)(R + SWZ(rowg + 0, colb, 512)) = (u16)(st[c][m][0]);
            *(u16*)(R + SWZ(rowg + 1, colb, 512)) = (u16)(st[c][m][0] >> 16);
            *(u16*)(R + SWZ(rowg + 2, colb, 512)) = (u16)(st[c][m][1]);
            *(u16*)(R + SWZ(rowg + 3, colb, 512)) = (u16)(st[c][m][1] >> 16);
        }
}

// Coalesced fp32 dump of a 32x256 bf16 LDS tile: full-line nontemporal streams.
__device__ __forceinline__ void dump_h(const char* __restrict__ R,
                                       float* __restrict__ g, int row0, int t) {
#pragma unroll
    for (int it = 0; it < 8; ++it) {
        int i = t + it * NTH;         // 2048 float4 = 32 rows x 64 float4
        int row = i >> 6, f4 = i & 63;
        u32x2 b = *(const u32x2*)(R + SWZ(row, f4 * 8, 512));
        f32x4 v;
        v[0] = __builtin_bit_cast(float, (b[0] & 0xFFFFu) << 16);
        v[1] = __builtin_bit_cast(float, b[0] & 0xFFFF0000u);
        v[2] = __builtin_bit_cast(float, (b[1] & 0xFFFFu) << 16);
        v[3] = __builtin_bit_cast(float, b[1] & 0xFFFF0000u);
        __builtin_nontemporal_store(v, (f32x4*)(g + (size_t)(row0 + row) * HD + f4 * 4));
    }
}

__global__ __launch_bounds__(NTH, 2) void gru_mfma(
    const float* __restrict__ x, const float* __restrict__ h,
    const float* __restrict__ bih0, const float* __restrict__ bhh0,
    const float* __restrict__ bih1, const float* __restrict__ bhh1,
    const float* __restrict__ bp, const float* __restrict__ bv,
    const u16* __restrict__ wb, float* __restrict__ out)
{
    __shared__ uint4 lds4[65536 / 16];           // 64 KB -> 2 blocks/CU (LDS-capped)
    char* lds = (char*)lds4;
    char* R1 = lds;             // x tile: 32 x 128 bf16, stride 256B (swz) = 8KB
    char* R2 = lds + 8192;      // h0 -> h0' -> h1' : 32 x 256 bf16, stride 512B = 16KB
    char* R3 = lds + 24576;     // h1 : 16KB
    char* WB0 = lds + 40960;    // weight slab dbuf: 2 x 12KB
    char* WB1 = lds + 53248;

    const int t = threadIdx.x;
    const int lane = t & 63;
    const int w = t >> 6;
    const int row0 = blockIdx.x * BM;

    const u16* W0x = wb + OFF_W0X;
    const u16* W0h = wb + OFF_W0H;
    const u16* W1x = wb + OFF_W1X;
    const u16* W1h = wb + OFF_W1H;
    const u16* Whd = wb + OFF_WHD;

    float* out_logits = out;
    float* out_value  = out + (size_t)NB * AD;
    float* out_h0     = out_value + NB;
    float* out_h1     = out_h0 + (size_t)NB * HD;

    // ---- stage x, h0, h1 (fp32 -> bf16, swizzled, nontemporal f32x4 reads) ----
    {
        const f32x4* xg = (const f32x4*)(x + (size_t)row0 * ID);
#pragma unroll
        for (int it = 0; it < 4; ++it) {
            int i = t + it * NTH;                 // 1024 float4
            f32x4 v = __builtin_nontemporal_load(xg + i);
            int rowi = i >> 5;                    // 32 float4/row
            int kb = (i & 31) * 8;                // bf16 byte offset
            u32x2 b;
            b[0] = (u32)f2bf(v[0]) | ((u32)f2bf(v[1]) << 16);
            b[1] = (u32)f2bf(v[2]) | ((u32)f2bf(v[3]) << 16);
            *(u32x2*)(R1 + SWZ(rowi, kb, 256)) = b;
        }
        const f32x4* h0g = (const f32x4*)(h + (size_t)row0 * HD);
        const f32x4* h1g = (const f32x4*)(h + (size_t)NB * HD + (size_t)row0 * HD);
#pragma unroll
        for (int it = 0; it < 8; ++it) {
            int i = t + it * NTH;                 // 2048 float4
            int rowi = i >> 6;                    // 64 float4/row
            int kb = (i & 63) * 8;
            f32x4 v0 = __builtin_nontemporal_load(h0g + i);
            u32x2 b0;
            b0[0] = (u32)f2bf(v0[0]) | ((u32)f2bf(v0[1]) << 16);
            b0[1] = (u32)f2bf(v0[2]) | ((u32)f2bf(v0[3]) << 16);
            *(u32x2*)(R2 + SWZ(rowi, kb, 512)) = b0;
            f32x4 v1 = __builtin_nontemporal_load(h1g + i);
            u32x2 b1;
            b1[0] = (u32)f2bf(v1[0]) | ((u32)f2bf(v1[1]) << 16);
            b1[1] = (u32)f2bf(v1[2]) | ((u32)f2bf(v1[3]) << 16);
            *(u32x2*)(R3 + SWZ(rowi, kb, 512)) = b1;
        }
    }
    __syncthreads();

    u32 st[4][MT][2];
    // ---- layer 0: A_x = x (R1, K=128), A_h = h0 (R2) ----
    gru_layer_v3<4>(R1, R2, WB0, WB1, W0x, W0h, bih0, bhh0, lane, w, st);
    __syncthreads();                 // all waves done reading h0 (R2)
    write_stash(R2, st, lane, w);    // R2 := h0' (bf16)
    __syncthreads();
    dump_h(R2, out_h0, row0, t);     // coalesced fp32 h0' writes

    // ---- layer 1: A_x = h0' (R2, K=256), A_h = h1 (R3) ----
    gru_layer_v3<8>(R2, R3, WB0, WB1, W1x, W1h, bih1, bhh1, lane, w, st);
    __syncthreads();                 // all waves done reading h0'/h1
    write_stash(R2, st, lane, w);    // R2 := h1' (bf16)
    __syncthreads();
    dump_h(R2, out_h1, row0, t);     // coalesced fp32 h1' writes

    // ---- heads: [logits(32) | value(1) | pad] = h1' @ Whd^T, N=48, K=256 ----
    if (w < MT) {
        const int m = w;                          // wave w -> rows m*16..+15
        const int arow = lane & 15;
        const int krow = (lane >> 4) * 8;
        float b0 = bp[arow], b1 = bp[16 + arow], b2 = bv[0];
        f32x4 acc[3];
        acc[0] = f32x4{b0, b0, b0, b0};
        acc[1] = f32x4{b1, b1, b1, b1};
        acc[2] = f32x4{b2, b2, b2, b2};
#pragma unroll
        for (int ks = 0; ks < 8; ++ks) {
            const int kb = ks * 32 + krow;
            const int row = m * 16 + arow;
            bf16x8 a = *(const bf16x8*)(R2 + SWZ(row, kb * 2, 512));
#pragma unroll
            for (int f = 0; f < 3; ++f) {
                bf16x8 wf = *(const bf16x8*)(Whd + (size_t)(f * 16 + arow) * HD + kb);
                acc[f] = MFMA(a, wf, acc[f]);
            }
        }
        const int rowg = m * 16 + ((lane >> 4) << 2);
#pragma unroll
        for (int q = 0; q < 4; ++q) {
            __builtin_nontemporal_store(acc[0][q],
                &out_logits[(size_t)(row0 + rowg + q) * AD + arow]);
            __builtin_nontemporal_store(acc[1][q],
                &out_logits[(size_t)(row0 + rowg + q) * AD + 16 + arow]);
        }
        if (arow == 0) {
#pragma unroll
            for (int q = 0; q < 4; ++q)
                __builtin_nontemporal_store(acc[2][q], &out_value[row0 + rowg + q]);
        }
    }
}

extern "C" void kernel_launch(void* const* d_in, const int* in_sizes, int n_in,
                              void* d_out, int out_size, void* d_ws, size_t ws_size,
                              hipStream_t stream) {
    const float* x    = (const float*)d_in[0];
    const float* h    = (const float*)d_in[1];
    const float* wih0 = (const float*)d_in[2];
    const float* whh0 = (const float*)d_in[3];
    const float* bih0 = (const float*)d_in[4];
    const float* bhh0 = (const float*)d_in[5];
    const float* wih1 = (const float*)d_in[6];
    const float* whh1 = (const float*)d_in[7];
    const float* bih1 = (const float*)d_in[8];
    const float* bhh1 = (const float*)d_in[9];
    const float* wp   = (const float*)d_in[10];
    const float* bp   = (const float*)d_in[11];
    const float* wv   = (const float*)d_in[12];
    const float* bv   = (const float*)d_in[13];

    u16* wb = (u16*)d_ws;   // 1.37 MB bf16 weights
    prep_weights<<<(W_TOTAL + 255) / 256, 256, 0, stream>>>(wih0, whh0, wih1, whh1, wp, wv, wb);
    gru_mfma<<<NBLK, NTH, 0, stream>>>(x, h, bih0, bhh0, bih1, bhh1, bp, bv, wb, (float*)d_out);
}